// Round 8
// baseline (216.946 us; speedup 1.0000x reference)
//
#include <hip/hip_runtime.h>
#include <hip/hip_bf16.h>
#include <cstdint>

typedef __attribute__((ext_vector_type(8))) short short8;    // 8 x bf16
typedef __attribute__((ext_vector_type(4))) float f32x4;
typedef __attribute__((ext_vector_type(4))) unsigned short u16x4;
typedef __attribute__((ext_vector_type(4))) int i32x4;

#define D_MODEL 512
#define S_LEN   4096
#define NB      2
#define NH      8
#define DK      64
#define MROWS   (NB * S_LEN)                    // 8192
#define MN      ((size_t)MROWS * D_MODEL)       // 4,194,304
#define WW      ((size_t)D_MODEL * D_MODEL)     // 262,144
// 1/sqrt(64) * log2(e) folded into Q projection; softmax runs in log2 domain
#define QSCALE  0.1803368801111204f

__device__ __forceinline__ float b2f(unsigned short u) {
    union { unsigned u; float f; } c; c.u = ((unsigned)u) << 16; return c.f;
}
__device__ __forceinline__ unsigned short f2b(float f) {   // RNE
    union { float f; unsigned u; } c; c.f = f;
    return (unsigned short)((c.u + 0x7FFFu + ((c.u >> 16) & 1u)) >> 16);
}
// pack two floats -> packed bf16 pair (round-half-up), low half = x
__device__ __forceinline__ unsigned pk2(float x, float y) {
    return __builtin_amdgcn_perm(__float_as_uint(y) + 0x8000u,
                                 __float_as_uint(x) + 0x8000u, 0x07060302u);
}
// pack two floats -> bf16 pair via HW cvt (RNE), low half = x
__device__ __forceinline__ unsigned pkcvt(float x, float y) {
    unsigned r;
    asm("v_cvt_pk_bf16_f32 %0, %1, %2" : "=v"(r) : "v"(x), "v"(y));
    return r;
}

#if __has_builtin(__builtin_amdgcn_exp2f)
#define EXP2F __builtin_amdgcn_exp2f
#else
#define EXP2F exp2f
#endif

__device__ __forceinline__ void gl_lds16(const unsigned short* g, unsigned short* l) {
    __builtin_amdgcn_global_load_lds(
        (__attribute__((address_space(1))) void*)g,
        (__attribute__((address_space(3))) void*)l, 16, 0, 0);
}

// counted-vmcnt barrier (T3/T4)
#define WAIT_BAR(cond, N)                                                  \
    do {                                                                   \
        if (cond) asm volatile("s_waitcnt vmcnt(" #N ")" ::: "memory");    \
        else      asm volatile("s_waitcnt vmcnt(0)" ::: "memory");         \
        __builtin_amdgcn_s_barrier();                                      \
    } while (0)

// ---- fused fp32->bf16 conversion of all 9 inputs, one launch ----
__global__ __launch_bounds__(256) void convert_all(
    const float* s0, const float* s1, const float* s2, const float* s3, const float* s4,
    const float* s5, const float* s6, const float* s7, const float* s8,
    unsigned short* d0, unsigned short* d1, unsigned short* d2, unsigned short* d3,
    unsigned short* d4, unsigned short* d5, unsigned short* d6, unsigned short* d7,
    unsigned short* d8)
{
    int b = blockIdx.x;
    const float* s; unsigned short* d; int n; int base;
    if      (b < 2048) { s = s0; d = d0; n = (int)MN; base = 0;    }
    else if (b < 2176) { s = s1; d = d1; n = (int)WW; base = 2048; }
    else if (b < 2177) { s = s2; d = d2; n = 512;     base = 2176; }
    else if (b < 2305) { s = s3; d = d3; n = (int)WW; base = 2177; }
    else if (b < 2306) { s = s4; d = d4; n = 512;     base = 2305; }
    else if (b < 2434) { s = s5; d = d5; n = (int)WW; base = 2306; }
    else if (b < 2435) { s = s6; d = d6; n = 512;     base = 2434; }
    else if (b < 2563) { s = s7; d = d7; n = (int)WW; base = 2435; }
    else               { s = s8; d = d8; n = 512;     base = 2563; }
    int i0 = (b - base) * 2048 + (int)threadIdx.x * 8;
    if (i0 + 8 <= n) {
        float4 a = *(const float4*)(s + i0);
        float4 c = *(const float4*)(s + i0 + 4);
        i32x4 p = {(int)pk2(a.x, a.y), (int)pk2(a.z, a.w),
                   (int)pk2(c.x, c.y), (int)pk2(c.z, c.w)};
        *(i32x4*)(d + i0) = p;
    } else {
        for (int i = i0; i < n; ++i) d[i] = f2b(s[i]);
    }
}

// ---- 128x128 tile GEMM body, triple-buffered counted-vmcnt pipeline ----
// mode: 0 = bf16 row-major, 1 = bf16 transposed (Yt[n*MROWS+m])
__device__ __forceinline__ void gemm_tile_body(
    const unsigned short* __restrict__ A, const unsigned short* __restrict__ W,
    const unsigned short* __restrict__ bias, void* __restrict__ Y,
    float scale, int mode, int tm, int tn,
    unsigned short* sA, unsigned short* sB)   // each 3 x 4096 shorts
{
    int t = threadIdx.x;
    int w = t >> 6, lane = t & 63, quad = lane >> 4, l16 = lane & 15;
    int wm = (w >> 1) * 64, wn = (w & 1) * 64;

    f32x4 acc[4][4];
    #pragma unroll
    for (int i = 0; i < 4; ++i)
        #pragma unroll
        for (int j = 0; j < 4; ++j) acc[i][j] = f32x4{0.f, 0.f, 0.f, 0.f};

    int srow = t >> 2, scol = (t & 3) * 8;
    const unsigned short* gA0 = A + (size_t)(tm + srow)      * D_MODEL + scol;
    const unsigned short* gA1 = A + (size_t)(tm + 64 + srow) * D_MODEL + scol;
    const unsigned short* gB0 = W + (size_t)(tn + srow)      * D_MODEL + scol;
    const unsigned short* gB1 = W + (size_t)(tn + 64 + srow) * D_MODEL + scol;

    auto stage = [&](int k0, int bi) {
        gl_lds16(gA0 + k0, sA + bi * 4096 + w * 512);
        gl_lds16(gA1 + k0, sA + bi * 4096 + 2048 + w * 512);
        gl_lds16(gB0 + k0, sB + bi * 4096 + w * 512);
        gl_lds16(gB1 + k0, sB + bi * 4096 + 2048 + w * 512);
    };
    stage(0, 0);
    stage(32, 1);

    const int nks = D_MODEL / 32;               // 16
    for (int ks = 0; ks < nks; ++ks) {
        WAIT_BAR(ks + 1 < nks, 4);              // tile ks done; ks+1 may fly
        if (ks + 2 < nks) stage((ks + 2) * 32, (ks + 2) % 3);
        const unsigned short* cA = sA + (ks % 3) * 4096;
        const unsigned short* cB = sB + (ks % 3) * 4096;

        short8 af[4], bf[4];
        #pragma unroll
        for (int i = 0; i < 4; ++i)
            af[i] = *(const short8*)(cA + (wm + i * 16 + l16) * 32 + quad * 8);
        #pragma unroll
        for (int j = 0; j < 4; ++j)
            bf[j] = *(const short8*)(cB + (wn + j * 16 + l16) * 32 + quad * 8);
        __builtin_amdgcn_s_setprio(1);
        #pragma unroll
        for (int i = 0; i < 4; ++i)
            #pragma unroll
            for (int j = 0; j < 4; ++j)
                acc[i][j] = __builtin_amdgcn_mfma_f32_16x16x32_bf16(af[i], bf[j], acc[i][j], 0, 0, 0);
        __builtin_amdgcn_s_setprio(0);
    }

    float bcol[4];
    #pragma unroll
    for (int j = 0; j < 4; ++j) bcol[j] = b2f(bias[tn + wn + j * 16 + l16]);

    if (mode == 0) {
        unsigned short* Yb = (unsigned short*)Y;
        #pragma unroll
        for (int i = 0; i < 4; ++i)
            #pragma unroll
            for (int r = 0; r < 4; ++r) {
                size_t row = tm + wm + i * 16 + quad * 4 + r;
                #pragma unroll
                for (int j = 0; j < 4; ++j)
                    Yb[row * D_MODEL + tn + wn + j * 16 + l16] = f2b((acc[i][j][r] + bcol[j]) * scale);
            }
    } else {
        unsigned short* Yb = (unsigned short*)Y;
        #pragma unroll
        for (int i = 0; i < 4; ++i)
            #pragma unroll
            for (int j = 0; j < 4; ++j) {
                size_t col = tn + wn + j * 16 + l16;
                u16x4 o;
                #pragma unroll
                for (int r = 0; r < 4; ++r) o[r] = f2b(acc[i][j][r] + bcol[j]);
                *(u16x4*)(Yb + col * MROWS + tm + wm + i * 16 + quad * 4) = o;
            }
    }
}

// fused Q/K/V projections: 768 blocks, XCD-chunked swizzle (768 = 8 x 96)
__global__ __launch_bounds__(256) void gemm_qkv(
    const unsigned short* __restrict__ x,
    const unsigned short* __restrict__ Wq, const unsigned short* __restrict__ bq, unsigned short* Qb,
    const unsigned short* __restrict__ Wk, const unsigned short* __restrict__ bk, unsigned short* Kb,
    const unsigned short* __restrict__ Wv, const unsigned short* __restrict__ bv, unsigned short* Vt)
{
    __shared__ unsigned short sA[3 * 4096];
    __shared__ unsigned short sB[3 * 4096];
    int bid = blockIdx.x;
    bid = (bid & 7) * 96 + (bid >> 3);          // XCD L2 locality
    int which = bid >> 8, tt = bid & 255;
    int tm = (tt >> 2) * 128, tn = (tt & 3) * 128;
    if (which == 0)      gemm_tile_body(x, Wq, bq, Qb, QSCALE, 0, tm, tn, sA, sB);
    else if (which == 1) gemm_tile_body(x, Wk, bk, Kb, 1.f,    0, tm, tn, sA, sB);
    else                 gemm_tile_body(x, Wv, bv, Vt, 1.f,    1, tm, tn, sA, sB);
}

// ---- flash attention v13: v10 loop, S-half split ACROSS blocks ----
// 512 blocks x 256 threads (4 waves); block = (b, h, qt in 16, half in 2);
// 64 q-rows per wave, S/2 keys per block.  2 independent blocks/CU -> the 2
// waves per SIMD come from DIFFERENT blocks (independent barriers) -> MFMA
// and VALU phases overlap across blocks (m114 mechanism).  Each block writes
// bf16 partial o_h/l_h (normalized by its own l) + fp32 l_h; final merge is
// a convex combination inside gemm_out_merge.
// K LDS: row i holds key k=(i&0x23)|((i>>2)&4)|((i<<1)&0x18), cols
// XOR-swizzled by ((row&7)*8) shorts; 3-deep buffers, vmcnt(4) counted wait.
#define KT 64
#define HBUF 4096            // shorts per K or V tile buffer (8 KB)

__global__ __launch_bounds__(256) void attn_v13(
    const unsigned short* __restrict__ Q, const unsigned short* __restrict__ Kb,
    const unsigned short* __restrict__ Vt, unsigned short* __restrict__ O0,
    unsigned short* __restrict__ O1, float* __restrict__ LS)
{
    __shared__ unsigned short sMem[6 * HBUF];   // 48 KB: K bufs 0-2, V bufs 3-5

    int t = threadIdx.x, w = t >> 6, lane = t & 63, quad = lane >> 4, l16 = lane & 15;
    int bid = blockIdx.x;
    bid = (bid & 7) * 64 + (bid >> 3);          // XCD L2 locality (512 = 8 x 64)
    int half = bid & 1;
    int qt = (bid >> 1) & 15;
    int bh = bid >> 5;
    int b = bh >> 3, h = bh & 7;
    int qw = qt * 256 + w * 64;
    int koff = half * (S_LEN / 2);
    const int iters = (S_LEN / 2) / KT;         // 32

    short8 aq[4][2];
    #pragma unroll
    for (int st = 0; st < 4; ++st)
        #pragma unroll
        for (int hf = 0; hf < 2; ++hf)
            aq[st][hf] = *(const short8*)(Q + (size_t)(b * S_LEN + qw + st * 16 + l16) * D_MODEL
                                            + h * DK + hf * 32 + quad * 8);

    float lsum[4] = {0.f, 0.f, 0.f, 0.f};
    f32x4 ot[4][4];
    #pragma unroll
    for (int st = 0; st < 4; ++st)
        #pragma unroll
        for (int dd = 0; dd < 4; ++dd) ot[st][dd] = f32x4{0.f, 0.f, 0.f, 0.f};
    const f32x4 fz = {0.f, 0.f, 0.f, 0.f};

    // staging: 2 K rows + 2 V rows per thread (4 gl_lds16 per wave per tile)
    int ra = w * 16 + (lane >> 3);
    int ka = (ra & 0x23) | ((ra >> 2) & 4) | ((ra << 1) & 0x18);
    int cswz = ((lane & 7) ^ (ra & 7)) * 8;     // XOR-swizzled 16B column (shorts)
    const unsigned short* gk0 = Kb + (size_t)(b * S_LEN + koff + ka) * D_MODEL + h * DK + cswz;
    const unsigned short* gv0 = Vt + (size_t)(h * DK + ra) * (size_t)MROWS + b * S_LEN + koff + cswz;
    unsigned short* kd = sMem + w * 1024;       // wave-uniform dest base
    unsigned short* vd = sMem + 3 * HBUF + w * 1024;

    auto stageT = [&](int it2) {
        size_t ko = (size_t)it2 * (64 * D_MODEL);
        int vo = it2 * 64;
        unsigned short* kdst = kd + (it2 % 3) * HBUF;
        unsigned short* vdst = vd + (it2 % 3) * HBUF;
        gl_lds16(gk0 + ko, kdst);
        gl_lds16(gk0 + ko + 16 * D_MODEL, kdst + 512);
        gl_lds16(gv0 + vo, vdst);
        gl_lds16(gv0 + vo + 8 * (size_t)MROWS, vdst + 512);
    };
    stageT(0);
    stageT(1);

    int swzr = (l16 & 7) << 3;                  // read-side swizzle, loop-invariant
    for (int it = 0; it < iters; ++it) {
        WAIT_BAR(it + 1 < iters, 4);            // tile it ready; it+1 may fly
        if (it + 2 < iters) stageT(it + 2);
        const unsigned short* K0 = sMem + (it % 3) * HBUF;
        const unsigned short* V0 = sMem + 3 * HBUF + (it % 3) * HBUF;

        // ---- S^T = K @ Q^T : 8 K-frag reads feed 32 MFMAs (4 st) ----
        f32x4 sc[4][4];
        __builtin_amdgcn_s_setprio(1);
        #pragma unroll
        for (int c = 0; c < 4; ++c) {
            const unsigned short* krow = K0 + (c * 16 + l16) * 64;
            short8 k0 = *(const short8*)(krow + ((quad * 8) ^ swzr));
            short8 k1 = *(const short8*)(krow + ((32 + quad * 8) ^ swzr));
            #pragma unroll
            for (int st = 0; st < 4; ++st) {
                sc[st][c] = __builtin_amdgcn_mfma_f32_16x16x32_bf16(k0, aq[st][0], fz, 0, 0, 0);
                sc[st][c] = __builtin_amdgcn_mfma_f32_16x16x32_bf16(k1, aq[st][1], sc[st][c], 0, 0, 0);
            }
        }
        __builtin_amdgcn_s_setprio(0);

        // ---- P = 2^S, pack to bf16 (HW cvt_pk), l accumulated in fp32 ----
        short8 cv[4][2];
        #pragma unroll
        for (int st = 0; st < 4; ++st) {
            unsigned pw[4][2];
            #pragma unroll
            for (int c = 0; c < 4; ++c) {
                float ps0 = EXP2F(sc[st][c][0]);
                float ps1 = EXP2F(sc[st][c][1]);
                float ps2 = EXP2F(sc[st][c][2]);
                float ps3 = EXP2F(sc[st][c][3]);
                lsum[st] += (ps0 + ps1) + (ps2 + ps3);
                pw[c][0] = pkcvt(ps0, ps1);
                pw[c][1] = pkcvt(ps2, ps3);
            }
            #pragma unroll
            for (int g = 0; g < 2; ++g) {
                union { unsigned u[4]; short8 s; } cu;
                cu.u[0] = pw[2 * g][0];     cu.u[1] = pw[2 * g][1];
                cu.u[2] = pw[2 * g + 1][0]; cu.u[3] = pw[2 * g + 1][1];
                cv[st][g] = cu.s;
            }
        }

        // ---- O^T += V^T @ P^T : 8 V-frag reads feed 32 MFMAs (4 st) ----
        __builtin_amdgcn_s_setprio(1);
        #pragma unroll
        for (int dd = 0; dd < 4; ++dd) {
            const unsigned short* vrow = V0 + (dd * 16 + l16) * 64;
            #pragma unroll
            for (int g = 0; g < 2; ++g) {
                short8 vf = *(const short8*)(vrow + ((g * 32 + quad * 8) ^ swzr));
                #pragma unroll
                for (int st = 0; st < 4; ++st)
                    ot[st][dd] = __builtin_amdgcn_mfma_f32_16x16x32_bf16(vf, cv[st][g], ot[st][dd], 0, 0, 0);
            }
        }
        __builtin_amdgcn_s_setprio(0);
    }

    // ---- per-half normalize, write bf16 partial + fp32 l (no block merge) ----
    unsigned short* Oh = half ? O1 : O0;
    float* LSh = LS + (size_t)half * MROWS * NH;
    #pragma unroll
    for (int st = 0; st < 4; ++st) {
        float l = lsum[st];
        l += __shfl_xor(l, 16);
        l += __shfl_xor(l, 32);
        float inv = 1.0f / l;
        size_t row = (size_t)(b * S_LEN + qw + st * 16 + l16);
        unsigned short* obase = Oh + row * D_MODEL + h * DK;
        #pragma unroll
        for (int dd = 0; dd < 4; ++dd) {
            u16x4 o;
            #pragma unroll
            for (int r = 0; r < 4; ++r) o[r] = f2b(ot[st][dd][r] * inv);
            *(u16x4*)(obase + dd * 16 + quad * 4) = o;
        }
        if (quad == 0) LSh[row * NH + h] = l;
    }
}

// ---- output projection + half merge: out = [(w0*o0n + w1*o1n)] @ Wo + bo ----
// 512 blocks (8 x 64 XCD-swizzled) x 256 thr; 64x128 tiles; A built on the
// fly from the two bf16 partials (weights w_h = l_h/(l0+l1), static head
// index under full unroll); B staged via gl_lds16; double-buffered.
// vmcnt ledger: at each top-of-iter the oldest 2 outstanding VMEM must be
// the B gl_lds of the buffer about to be read -> (a) sched_barrier(0) pins
// the A-prefetch loads AFTER the gl_lds issues (compiler may not hoist);
// (b) the LAST iteration has no A-prefetch outstanding, so it must drain
// with vmcnt(0) (R7 bug: unconditional vmcnt(2) raced the final B DMA).
__global__ __launch_bounds__(256) void gemm_out_merge(
    const unsigned short* __restrict__ O0, const unsigned short* __restrict__ O1,
    const float* __restrict__ LS, const unsigned short* __restrict__ Wo,
    const unsigned short* __restrict__ bo, float* __restrict__ out)
{
    __shared__ unsigned short sA[2 * 2048];     // 64 x 32 per buffer
    __shared__ unsigned short sB[2 * 4096];     // 128 x 32 per buffer
    int t = threadIdx.x;
    int w = t >> 6, lane = t & 63, quad = lane >> 4, l16 = lane & 15;
    int bid = blockIdx.x;
    bid = (bid & 7) * 64 + (bid >> 3);          // XCD L2 locality
    int tm = (bid >> 2) * 64, tn = (bid & 3) * 128;

    f32x4 acc[4][2];
    #pragma unroll
    for (int i = 0; i < 4; ++i)
        #pragma unroll
        for (int j = 0; j < 2; ++j) acc[i][j] = f32x4{0.f, 0.f, 0.f, 0.f};

    int srow = t >> 2, scol = (t & 3) * 8;
    int r = tm + srow;
    float w0h[8], w1h[8];
    #pragma unroll
    for (int hh = 0; hh < 8; ++hh) {
        float l0 = LS[(size_t)r * NH + hh];
        float l1 = LS[(size_t)MROWS * NH + (size_t)r * NH + hh];
        float inv = 1.0f / (l0 + l1);
        w0h[hh] = l0 * inv;
        w1h[hh] = l1 * inv;
    }
    const unsigned short* gA0 = O0 + (size_t)r * D_MODEL + scol;
    const unsigned short* gA1 = O1 + (size_t)r * D_MODEL + scol;
    const unsigned short* gB0 = Wo + (size_t)(tn + srow)      * D_MODEL + scol;
    const unsigned short* gB1 = Wo + (size_t)(tn + 64 + srow) * D_MODEL + scol;
    unsigned short* myA = sA + srow * 32 + scol;

    auto putA = [&](i32x4 a0, i32x4 a1, float w0, float w1, int bi) {
        unsigned rr[4];
        #pragma unroll
        for (int k = 0; k < 4; ++k) {
            unsigned u0 = (unsigned)a0[k], u1 = (unsigned)a1[k];
            float x0 = __uint_as_float(u0 << 16);
            float x1 = __uint_as_float(u0 & 0xFFFF0000u);
            float y0 = __uint_as_float(u1 << 16);
            float y1 = __uint_as_float(u1 & 0xFFFF0000u);
            rr[k] = pkcvt(w0 * x0 + w1 * y0, w0 * x1 + w1 * y1);
        }
        i32x4 pv = {(int)rr[0], (int)rr[1], (int)rr[2], (int)rr[3]};
        *(i32x4*)(myA + bi * 2048) = pv;
    };

    // prologue: A(0) merged into buf0, B(0) staged, A(1) regs in flight
    i32x4 a0 = *(const i32x4*)(gA0);
    i32x4 a1 = *(const i32x4*)(gA1);
    putA(a0, a1, w0h[0], w1h[0], 0);
    gl_lds16(gB0, sB + w * 512);
    gl_lds16(gB1, sB + 2048 + w * 512);
    __builtin_amdgcn_sched_barrier(0);          // pin A-prefetch after gl_lds
    a0 = *(const i32x4*)(gA0 + 32);
    a1 = *(const i32x4*)(gA1 + 32);

    #pragma unroll
    for (int ks = 0; ks < 16; ++ks) {
        // buf[ks&1] ready: B gl_lds done; at ks=15 no A-prefetch is in
        // flight, so drain fully (conditional wait — R7's race fix).
        if (ks + 1 < 16) asm volatile("s_waitcnt vmcnt(2) lgkmcnt(0)" ::: "memory");
        else             asm volatile("s_waitcnt vmcnt(0) lgkmcnt(0)" ::: "memory");
        __builtin_amdgcn_s_barrier();
        const unsigned short* cA = sA + (ks & 1) * 2048;
        const unsigned short* cB = sB + (ks & 1) * 4096;

        short8 af[4], bf[2];
        #pragma unroll
        for (int i = 0; i < 4; ++i)
            af[i] = *(const short8*)(cA + (i * 16 + l16) * 32 + quad * 8);
        #pragma unroll
        for (int j = 0; j < 2; ++j)
            bf[j] = *(const short8*)(cB + (w * 32 + j * 16 + l16) * 32 + quad * 8);
        __builtin_amdgcn_s_setprio(1);
        #pragma unroll
        for (int i = 0; i < 4; ++i)
            #pragma unroll
            for (int j = 0; j < 2; ++j)
                acc[i][j] = __builtin_amdgcn_mfma_f32_16x16x32_bf16(af[i], bf[j], acc[i][j], 0, 0, 0);
        __builtin_amdgcn_s_setprio(0);

        if (ks + 1 < 16) {
            int nb = (ks + 1) & 1;
            asm volatile("s_waitcnt vmcnt(0)" ::: "memory");   // A regs arrived
            putA(a0, a1, w0h[(ks + 1) >> 1], w1h[(ks + 1) >> 1], nb);
            gl_lds16(gB0 + (ks + 1) * 32, sB + nb * 4096 + w * 512);
            gl_lds16(gB1 + (ks + 1) * 32, sB + nb * 4096 + 2048 + w * 512);
            __builtin_amdgcn_sched_barrier(0);  // pin A-prefetch after gl_lds
            if (ks + 2 < 16) {
                a0 = *(const i32x4*)(gA0 + (ks + 2) * 32);
                a1 = *(const i32x4*)(gA1 + (ks + 2) * 32);
            }
        }
    }

    float bcol[2];
    #pragma unroll
    for (int j = 0; j < 2; ++j) bcol[j] = b2f(bo[tn + w * 32 + j * 16 + l16]);
    #pragma unroll
    for (int i = 0; i < 4; ++i)
        #pragma unroll
        for (int r2 = 0; r2 < 4; ++r2) {
            size_t row = tm + i * 16 + quad * 4 + r2;
            #pragma unroll
            for (int j = 0; j < 2; ++j)
                out[row * D_MODEL + tn + w * 32 + j * 16 + l16] = acc[i][j][r2] + bcol[j];
        }
}

extern "C" void kernel_launch(void* const* d_in, const int* in_sizes, int n_in,
                              void* d_out, int out_size, void* d_ws, size_t ws_size,
                              hipStream_t stream)
{
    unsigned char* ws = (unsigned char*)d_ws;
    unsigned short* xb  = (unsigned short*)ws;       // 8 MB (reused as O0)
    unsigned short* Wqb = xb  + MN;
    unsigned short* Wkb = Wqb + WW;
    unsigned short* Wvb = Wkb + WW;
    unsigned short* Wob = Wvb + WW;
    unsigned short* bqb = Wob + WW;
    unsigned short* bkb = bqb + D_MODEL;
    unsigned short* bvb = bkb + D_MODEL;
    unsigned short* bob = bvb + D_MODEL;
    unsigned short* Qb  = bob + D_MODEL;             // 8 MB
    unsigned short* Kbf = Qb  + MN;                  // 8 MB
    unsigned short* Vt  = Kbf + MN;                  // 8 MB ([e][n])
    unsigned short* O0  = xb;                        // alias, xb dead after QKV
    unsigned short* O1  = Vt  + MN;                  // 8 MB
    float*          LS  = (float*)(O1 + MN);         // 512 KB (2 x 8192 x 8 f32)

    dim3 blk(256);
    hipLaunchKernelGGL(convert_all, dim3(2564), blk, 0, stream,
        (const float*)d_in[0], (const float*)d_in[1], (const float*)d_in[2],
        (const float*)d_in[3], (const float*)d_in[4], (const float*)d_in[5],
        (const float*)d_in[6], (const float*)d_in[7], (const float*)d_in[8],
        xb, Wqb, bqb, Wkb, bkb, Wvb, bvb, Wob, bob);

    hipLaunchKernelGGL(gemm_qkv, dim3(768), blk, 0, stream,
        xb, Wqb, bqb, Qb, Wkb, bkb, Kbf, Wvb, bvb, Vt);

    hipLaunchKernelGGL(attn_v13, dim3(512), blk, 0, stream,
        Qb, Kbf, Vt, O0, O1, LS);

    hipLaunchKernelGGL(gemm_out_merge, dim3(512), blk, 0, stream,
        O0, O1, LS, Wob, bob, (float*)d_out);
}

// Round 9
// 180.527 us; speedup vs baseline: 1.2017x; 1.2017x over previous
//
#include <hip/hip_runtime.h>
#include <hip/hip_bf16.h>
#include <cstdint>

typedef __attribute__((ext_vector_type(8))) short short8;    // 8 x bf16
typedef __attribute__((ext_vector_type(4))) float f32x4;
typedef __attribute__((ext_vector_type(4))) unsigned short u16x4;
typedef __attribute__((ext_vector_type(4))) int i32x4;

#define D_MODEL 512
#define S_LEN   4096
#define NB      2
#define NH      8
#define DK      64
#define MROWS   (NB * S_LEN)                    // 8192
#define MN      ((size_t)MROWS * D_MODEL)       // 4,194,304
#define WW      ((size_t)D_MODEL * D_MODEL)     // 262,144
// 1/sqrt(64) * log2(e) folded into Q projection; softmax runs in log2 domain
#define QSCALE  0.1803368801111204f

__device__ __forceinline__ float b2f(unsigned short u) {
    union { unsigned u; float f; } c; c.u = ((unsigned)u) << 16; return c.f;
}
__device__ __forceinline__ unsigned short f2b(float f) {   // RNE
    union { float f; unsigned u; } c; c.f = f;
    return (unsigned short)((c.u + 0x7FFFu + ((c.u >> 16) & 1u)) >> 16);
}
// pack two floats -> packed bf16 pair (round-half-up), low half = x
__device__ __forceinline__ unsigned pk2(float x, float y) {
    return __builtin_amdgcn_perm(__float_as_uint(y) + 0x8000u,
                                 __float_as_uint(x) + 0x8000u, 0x07060302u);
}
// pack two floats -> bf16 pair via HW cvt (RNE), low half = x
__device__ __forceinline__ unsigned pkcvt(float x, float y) {
    unsigned r;
    asm("v_cvt_pk_bf16_f32 %0, %1, %2" : "=v"(r) : "v"(x), "v"(y));
    return r;
}

#if __has_builtin(__builtin_amdgcn_exp2f)
#define EXP2F __builtin_amdgcn_exp2f
#else
#define EXP2F exp2f
#endif

__device__ __forceinline__ void gl_lds16(const unsigned short* g, unsigned short* l) {
    __builtin_amdgcn_global_load_lds(
        (__attribute__((address_space(1))) void*)g,
        (__attribute__((address_space(3))) void*)l, 16, 0, 0);
}

// counted-vmcnt barrier (T3/T4)
#define WAIT_BAR(cond, N)                                                  \
    do {                                                                   \
        if (cond) asm volatile("s_waitcnt vmcnt(" #N ")" ::: "memory");    \
        else      asm volatile("s_waitcnt vmcnt(0)" ::: "memory");         \
        __builtin_amdgcn_s_barrier();                                      \
    } while (0)

// ---- fused fp32->bf16 conversion of all 9 inputs, one launch ----
__global__ __launch_bounds__(256) void convert_all(
    const float* s0, const float* s1, const float* s2, const float* s3, const float* s4,
    const float* s5, const float* s6, const float* s7, const float* s8,
    unsigned short* d0, unsigned short* d1, unsigned short* d2, unsigned short* d3,
    unsigned short* d4, unsigned short* d5, unsigned short* d6, unsigned short* d7,
    unsigned short* d8)
{
    int b = blockIdx.x;
    const float* s; unsigned short* d; int n; int base;
    if      (b < 2048) { s = s0; d = d0; n = (int)MN; base = 0;    }
    else if (b < 2176) { s = s1; d = d1; n = (int)WW; base = 2048; }
    else if (b < 2177) { s = s2; d = d2; n = 512;     base = 2176; }
    else if (b < 2305) { s = s3; d = d3; n = (int)WW; base = 2177; }
    else if (b < 2306) { s = s4; d = d4; n = 512;     base = 2305; }
    else if (b < 2434) { s = s5; d = d5; n = (int)WW; base = 2306; }
    else if (b < 2435) { s = s6; d = d6; n = 512;     base = 2434; }
    else if (b < 2563) { s = s7; d = d7; n = (int)WW; base = 2435; }
    else               { s = s8; d = d8; n = 512;     base = 2563; }
    int i0 = (b - base) * 2048 + (int)threadIdx.x * 8;
    if (i0 + 8 <= n) {
        float4 a = *(const float4*)(s + i0);
        float4 c = *(const float4*)(s + i0 + 4);
        i32x4 p = {(int)pk2(a.x, a.y), (int)pk2(a.z, a.w),
                   (int)pk2(c.x, c.y), (int)pk2(c.z, c.w)};
        *(i32x4*)(d + i0) = p;
    } else {
        for (int i = i0; i < n; ++i) d[i] = f2b(s[i]);
    }
}

// ---- 64x128 tile GEMM body, triple-buffered counted-vmcnt pipeline ----
// Y[m,n] = (sum_k A[m,k] W[n,k] + bias)*scale
// mode: 0 = bf16 row-major, 1 = bf16 transposed (Yt[n*MROWS+m]), 2 = fp32
// 256 threads (4 waves); wave w owns output cols [w*32, w*32+32).
// 36 KB LDS -> 4 blocks/CU co-resident: cross-block MFMA/staging overlap.
__device__ __forceinline__ void gemm64_body(
    const unsigned short* __restrict__ A, const unsigned short* __restrict__ W,
    const unsigned short* __restrict__ bias, void* __restrict__ Y,
    float scale, int mode, int tm, int tn,
    unsigned short* sA, unsigned short* sB)   // 3 x 2048 / 3 x 4096 shorts
{
    int t = threadIdx.x;
    int w = t >> 6, lane = t & 63, quad = lane >> 4, l16 = lane & 15;

    f32x4 acc[4][2];
    #pragma unroll
    for (int i = 0; i < 4; ++i)
        #pragma unroll
        for (int j = 0; j < 2; ++j) acc[i][j] = f32x4{0.f, 0.f, 0.f, 0.f};

    int srow = t >> 2, scol = (t & 3) * 8;
    const unsigned short* gA  = A + (size_t)(tm + srow)      * D_MODEL + scol;
    const unsigned short* gB0 = W + (size_t)(tn + srow)      * D_MODEL + scol;
    const unsigned short* gB1 = W + (size_t)(tn + 64 + srow) * D_MODEL + scol;

    auto stage = [&](int k0, int bi) {
        gl_lds16(gA  + k0, sA + bi * 2048 + w * 512);
        gl_lds16(gB0 + k0, sB + bi * 4096 + w * 512);
        gl_lds16(gB1 + k0, sB + bi * 4096 + 2048 + w * 512);
    };
    stage(0, 0);
    stage(32, 1);

    const int nks = D_MODEL / 32;               // 16
    for (int ks = 0; ks < nks; ++ks) {
        WAIT_BAR(ks + 1 < nks, 3);              // tile ks done; ks+1 may fly
        if (ks + 2 < nks) stage((ks + 2) * 32, (ks + 2) % 3);
        const unsigned short* cA = sA + (ks % 3) * 2048;
        const unsigned short* cB = sB + (ks % 3) * 4096;

        short8 af[4], bf[2];
        #pragma unroll
        for (int i = 0; i < 4; ++i)
            af[i] = *(const short8*)(cA + (i * 16 + l16) * 32 + quad * 8);
        #pragma unroll
        for (int j = 0; j < 2; ++j)
            bf[j] = *(const short8*)(cB + (w * 32 + j * 16 + l16) * 32 + quad * 8);
        __builtin_amdgcn_s_setprio(1);
        #pragma unroll
        for (int i = 0; i < 4; ++i)
            #pragma unroll
            for (int j = 0; j < 2; ++j)
                acc[i][j] = __builtin_amdgcn_mfma_f32_16x16x32_bf16(af[i], bf[j], acc[i][j], 0, 0, 0);
        __builtin_amdgcn_s_setprio(0);
    }

    float bcol[2];
    #pragma unroll
    for (int j = 0; j < 2; ++j) bcol[j] = b2f(bias[tn + w * 32 + j * 16 + l16]);

    if (mode == 0) {
        unsigned short* Yb = (unsigned short*)Y;
        #pragma unroll
        for (int i = 0; i < 4; ++i)
            #pragma unroll
            for (int r = 0; r < 4; ++r) {
                size_t row = tm + i * 16 + quad * 4 + r;
                #pragma unroll
                for (int j = 0; j < 2; ++j)
                    Yb[row * D_MODEL + tn + w * 32 + j * 16 + l16] = f2b((acc[i][j][r] + bcol[j]) * scale);
            }
    } else if (mode == 1) {
        unsigned short* Yb = (unsigned short*)Y;
        #pragma unroll
        for (int i = 0; i < 4; ++i)
            #pragma unroll
            for (int j = 0; j < 2; ++j) {
                size_t col = tn + w * 32 + j * 16 + l16;
                u16x4 o;
                #pragma unroll
                for (int r = 0; r < 4; ++r) o[r] = f2b(acc[i][j][r] + bcol[j]);
                *(u16x4*)(Yb + col * MROWS + tm + i * 16 + quad * 4) = o;
            }
    } else {
        float* Yf = (float*)Y;
        #pragma unroll
        for (int i = 0; i < 4; ++i)
            #pragma unroll
            for (int r = 0; r < 4; ++r) {
                size_t row = tm + i * 16 + quad * 4 + r;
                #pragma unroll
                for (int j = 0; j < 2; ++j)
                    Yf[row * D_MODEL + tn + w * 32 + j * 16 + l16] = acc[i][j][r] + bcol[j];
            }
    }
}

// fused Q/K/V projections: 64x128 tiles, 3 x 512 = 1536 blocks (8 x 192
// XCD-chunked) -> 4 blocks/CU co-resident (36 KB LDS each).
__global__ __launch_bounds__(256) void gemm_qkv(
    const unsigned short* __restrict__ x,
    const unsigned short* __restrict__ Wq, const unsigned short* __restrict__ bq, unsigned short* Qb,
    const unsigned short* __restrict__ Wk, const unsigned short* __restrict__ bk, unsigned short* Kb,
    const unsigned short* __restrict__ Wv, const unsigned short* __restrict__ bv, unsigned short* Vt)
{
    __shared__ unsigned short sA[3 * 2048];
    __shared__ unsigned short sB[3 * 4096];
    int bid = blockIdx.x;
    bid = (bid & 7) * 192 + (bid >> 3);         // XCD L2 locality (1536 = 8 x 192)
    int which = bid >> 9, tt = bid & 511;
    int tm = (tt >> 2) * 64, tn = (tt & 3) * 128;
    if (which == 0)      gemm64_body(x, Wq, bq, Qb, QSCALE, 0, tm, tn, sA, sB);
    else if (which == 1) gemm64_body(x, Wk, bk, Kb, 1.f,    0, tm, tn, sA, sB);
    else                 gemm64_body(x, Wv, bv, Vt, 1.f,    1, tm, tn, sA, sB);
}

// ---- output projection: 64x128 tiles -> 512 blocks (8 x 64), fp32 out ----
__global__ __launch_bounds__(256) void gemm_out(
    const unsigned short* __restrict__ At, const unsigned short* __restrict__ Wo,
    const unsigned short* __restrict__ bo, float* __restrict__ out)
{
    __shared__ unsigned short sA[3 * 2048];
    __shared__ unsigned short sB[3 * 4096];
    int bid = blockIdx.x;
    bid = (bid & 7) * 64 + (bid >> 3);          // XCD L2 locality
    int tm = (bid >> 2) * 64, tn = (bid & 3) * 128;
    gemm64_body(At, Wo, bo, out, 1.f, 2, tm, tn, sA, sB);
}

// ---- flash attention v10 (proven 71.6 us) + bijective XCD swizzle ----
// 256 blocks x 512 threads (2 key-halves x 4 q-slots); 64 q-rows per wave.
// K LDS: row i holds key k=(i&0x23)|((i>>2)&4)|((i<<1)&0x18), cols
// XOR-swizzled by ((row&7)*8) shorts; 3-deep buffers, vmcnt(4) counted wait.
#define KT 64
#define HBUF 4096            // shorts per K or V tile buffer (8 KB)

__global__ __launch_bounds__(512, 2) void attn_v10(
    const unsigned short* __restrict__ Q, const unsigned short* __restrict__ Kb,
    const unsigned short* __restrict__ Vt, unsigned short* __restrict__ O)
{
    __shared__ unsigned short sMem[12 * HBUF];  // 96 KB: K bufs 0-5, V bufs 6-11

    int t = threadIdx.x, w = t >> 6, lane = t & 63, quad = lane >> 4, l16 = lane & 15;
    int half = w >> 2, wl = w & 3;
    int bid = blockIdx.x;
    bid = (bid & 7) * 32 + (bid >> 3);          // XCD L2 locality (256 = 8 x 32)
    int qt = bid & 15;
    int bh = bid >> 4;
    int b = bh >> 3, h = bh & 7;
    int qw = qt * 256 + wl * 64;
    int koff = half * (S_LEN / 2);
    const int iters = (S_LEN / 2) / KT;         // 32

    short8 aq[4][2];
    #pragma unroll
    for (int st = 0; st < 4; ++st)
        #pragma unroll
        for (int hf = 0; hf < 2; ++hf)
            aq[st][hf] = *(const short8*)(Q + (size_t)(b * S_LEN + qw + st * 16 + l16) * D_MODEL
                                            + h * DK + hf * 32 + quad * 8);

    float lsum[4] = {0.f, 0.f, 0.f, 0.f};
    f32x4 ot[4][4];
    #pragma unroll
    for (int st = 0; st < 4; ++st)
        #pragma unroll
        for (int dd = 0; dd < 4; ++dd) ot[st][dd] = f32x4{0.f, 0.f, 0.f, 0.f};
    const f32x4 fz = {0.f, 0.f, 0.f, 0.f};

    // staging: 2 K rows + 2 V rows per thread (4 gl_lds16 per thread per tile)
    int ra = wl * 16 + (lane >> 3);
    int rb = ra + 8;
    int ka = (ra & 0x23) | ((ra >> 2) & 4) | ((ra << 1) & 0x18);
    int kb2 = (rb & 0x23) | ((rb >> 2) & 4) | ((rb << 1) & 0x18);
    int cswz = ((lane & 7) ^ (ra & 7)) * 8;     // XOR-swizzled 16B column (shorts)
    const unsigned short* gk0 = Kb + (size_t)(b * S_LEN + koff + ka)  * D_MODEL + h * DK + cswz;
    const unsigned short* gk1 = Kb + (size_t)(b * S_LEN + koff + kb2) * D_MODEL + h * DK + cswz;
    const unsigned short* gv0 = Vt + (size_t)(h * DK + ra) * (size_t)MROWS + b * S_LEN + koff + cswz;
    const unsigned short* gv1 = Vt + (size_t)(h * DK + rb) * (size_t)MROWS + b * S_LEN + koff + cswz;
    unsigned short* sKh = sMem + half * 3 * HBUF;
    unsigned short* sVh = sMem + 6 * HBUF + half * 3 * HBUF;
    unsigned short* kd = sKh + wl * 1024;       // wave-uniform dest base
    unsigned short* vd = sVh + wl * 1024;

    auto stageT = [&](int it2) {
        size_t ko = (size_t)it2 * (64 * D_MODEL);
        int vo = it2 * 64;
        unsigned short* kdst = kd + (it2 % 3) * HBUF;
        unsigned short* vdst = vd + (it2 % 3) * HBUF;
        gl_lds16(gk0 + ko, kdst);
        gl_lds16(gk1 + ko, kdst + 512);
        gl_lds16(gv0 + vo, vdst);
        gl_lds16(gv1 + vo, vdst + 512);
    };
    stageT(0);
    stageT(1);

    int swzr = (l16 & 7) << 3;                  // read-side swizzle, loop-invariant
    for (int it = 0; it < iters; ++it) {
        WAIT_BAR(it + 1 < iters, 4);            // tile it ready; it+1 may fly
        if (it + 2 < iters) stageT(it + 2);
        const unsigned short* K0 = sKh + (it % 3) * HBUF;
        const unsigned short* V0 = sVh + (it % 3) * HBUF;

        // ---- S^T = K @ Q^T : 8 K-frag reads feed 32 MFMAs (4 st) ----
        f32x4 sc[4][4];
        __builtin_amdgcn_s_setprio(1);
        #pragma unroll
        for (int c = 0; c < 4; ++c) {
            const unsigned short* krow = K0 + (c * 16 + l16) * 64;
            short8 k0 = *(const short8*)(krow + ((quad * 8) ^ swzr));
            short8 k1 = *(const short8*)(krow + ((32 + quad * 8) ^ swzr));
            #pragma unroll
            for (int st = 0; st < 4; ++st) {
                sc[st][c] = __builtin_amdgcn_mfma_f32_16x16x32_bf16(k0, aq[st][0], fz, 0, 0, 0);
                sc[st][c] = __builtin_amdgcn_mfma_f32_16x16x32_bf16(k1, aq[st][1], sc[st][c], 0, 0, 0);
            }
        }
        __builtin_amdgcn_s_setprio(0);

        // ---- P = 2^S, pack to bf16 (HW cvt_pk), l accumulated in fp32 ----
        short8 cv[4][2];
        #pragma unroll
        for (int st = 0; st < 4; ++st) {
            unsigned pw[4][2];
            #pragma unroll
            for (int c = 0; c < 4; ++c) {
                float ps0 = EXP2F(sc[st][c][0]);
                float ps1 = EXP2F(sc[st][c][1]);
                float ps2 = EXP2F(sc[st][c][2]);
                float ps3 = EXP2F(sc[st][c][3]);
                lsum[st] += (ps0 + ps1) + (ps2 + ps3);
                pw[c][0] = pkcvt(ps0, ps1);
                pw[c][1] = pkcvt(ps2, ps3);
            }
            #pragma unroll
            for (int g = 0; g < 2; ++g) {
                union { unsigned u[4]; short8 s; } cu;
                cu.u[0] = pw[2 * g][0];     cu.u[1] = pw[2 * g][1];
                cu.u[2] = pw[2 * g + 1][0]; cu.u[3] = pw[2 * g + 1][1];
                cv[st][g] = cu.s;
            }
        }

        // ---- O^T += V^T @ P^T : 8 V-frag reads feed 32 MFMAs (4 st) ----
        __builtin_amdgcn_s_setprio(1);
        #pragma unroll
        for (int dd = 0; dd < 4; ++dd) {
            const unsigned short* vrow = V0 + (dd * 16 + l16) * 64;
            #pragma unroll
            for (int g = 0; g < 2; ++g) {
                short8 vf = *(const short8*)(vrow + ((g * 32 + quad * 8) ^ swzr));
                #pragma unroll
                for (int st = 0; st < 4; ++st)
                    ot[st][dd] = __builtin_amdgcn_mfma_f32_16x16x32_bf16(vf, cv[st][g], ot[st][dd], 0, 0, 0);
            }
        }
        __builtin_amdgcn_s_setprio(0);
    }

    // ---- merge halves through LDS (2 st per round), normalize, write bf16 ----
    float* scr  = (float*)sMem;                 // 2 st x 4 dd x 256 x f32x4 = 32 KB
    float* lscr = scr + 8192;                   // 2 x 256 floats
    #pragma unroll
    for (int sp = 0; sp < 2; ++sp) {
        __syncthreads();
        if (half == 1) {
            #pragma unroll
            for (int s2 = 0; s2 < 2; ++s2) {
                int st = sp * 2 + s2;
                #pragma unroll
                for (int dd = 0; dd < 4; ++dd)
                    *(f32x4*)(scr + ((s2 * 4 + dd) * 256 + wl * 64 + lane) * 4) = ot[st][dd];
                lscr[s2 * 256 + wl * 64 + lane] = lsum[st];
            }
        }
        __syncthreads();
        if (half == 0) {
            #pragma unroll
            for (int s2 = 0; s2 < 2; ++s2) {
                int st = sp * 2 + s2;
                float l = lsum[st] + lscr[s2 * 256 + wl * 64 + lane];
                l += __shfl_xor(l, 16);
                l += __shfl_xor(l, 32);
                float inv = 1.0f / l;
                size_t row = (size_t)(b * S_LEN + qw + st * 16 + l16);
                unsigned short* obase = O + row * D_MODEL + h * DK;
                #pragma unroll
                for (int dd = 0; dd < 4; ++dd) {
                    f32x4 po = *(const f32x4*)(scr + ((s2 * 4 + dd) * 256 + wl * 64 + lane) * 4);
                    f32x4 s = ot[st][dd] + po;
                    u16x4 o;
                    #pragma unroll
                    for (int r = 0; r < 4; ++r) o[r] = f2b(s[r] * inv);
                    *(u16x4*)(obase + dd * 16 + quad * 4) = o;
                }
            }
        }
    }
}

extern "C" void kernel_launch(void* const* d_in, const int* in_sizes, int n_in,
                              void* d_out, int out_size, void* d_ws, size_t ws_size,
                              hipStream_t stream)
{
    unsigned char* ws = (unsigned char*)d_ws;
    unsigned short* xb  = (unsigned short*)ws;       // 8 MB (reused as At)
    unsigned short* Wqb = xb  + MN;
    unsigned short* Wkb = Wqb + WW;
    unsigned short* Wvb = Wkb + WW;
    unsigned short* Wob = Wvb + WW;
    unsigned short* bqb = Wob + WW;
    unsigned short* bkb = bqb + D_MODEL;
    unsigned short* bvb = bkb + D_MODEL;
    unsigned short* bob = bvb + D_MODEL;
    unsigned short* Qb  = bob + D_MODEL;             // 8 MB
    unsigned short* Kbf = Qb  + MN;                  // 8 MB
    unsigned short* Vt  = Kbf + MN;                  // 8 MB ([e][n])
    unsigned short* At  = xb;                        // alias, xb dead after QKV

    dim3 blk(256);
    hipLaunchKernelGGL(convert_all, dim3(2564), blk, 0, stream,
        (const float*)d_in[0], (const float*)d_in[1], (const float*)d_in[2],
        (const float*)d_in[3], (const float*)d_in[4], (const float*)d_in[5],
        (const float*)d_in[6], (const float*)d_in[7], (const float*)d_in[8],
        xb, Wqb, bqb, Wkb, bkb, Wvb, bvb, Wob, bob);

    hipLaunchKernelGGL(gemm_qkv, dim3(1536), blk, 0, stream,
        xb, Wqb, bqb, Qb, Wkb, bkb, Kbf, Wvb, bvb, Vt);

    hipLaunchKernelGGL(attn_v10, dim3(256), dim3(512), 0, stream,
        Qb, Kbf, Vt, At);

    hipLaunchKernelGGL(gemm_out, dim3(512), blk, 0, stream,
        At, Wob, bob, (float*)d_out);
}